// Round 1
// baseline (440.490 us; speedup 1.0000x reference)
//
#include <hip/hip_runtime.h>

typedef __bf16 bf16_t;
typedef __bf16 bf16x8 __attribute__((ext_vector_type(8)));
typedef __bf16 bf16x4 __attribute__((ext_vector_type(4)));
typedef float f32x4 __attribute__((ext_vector_type(4)));

#define DEV static __device__ __forceinline__

DEV void gload16(const void* g, void* lds) {
  __builtin_amdgcn_global_load_lds((__attribute__((address_space(1))) void*)g,
                                   (__attribute__((address_space(3))) void*)lds, 16, 0, 0);
}

DEV f32x4 mfma16(bf16x8 a, bf16x8 b, f32x4 c) {
  return __builtin_amdgcn_mfma_f32_16x16x32_bf16(a, b, c, 0, 0, 0);
}

// ---------------- f32 -> bf16 convert ----------------
__global__ __launch_bounds__(256) void k_cvt_bf16(const float* __restrict__ in,
                                                  bf16_t* __restrict__ out, int n) {
  int i = (blockIdx.x * 256 + threadIdx.x) * 4;
  if (i + 3 < n) {
    float4 v = *(const float4*)(in + i);
    bf16x4 o;
    o[0] = (bf16_t)v.x; o[1] = (bf16_t)v.y; o[2] = (bf16_t)v.z; o[3] = (bf16_t)v.w;
    *(bf16x4*)(out + i) = o;
  }
}

// ---------------- transpose f32 [R][C] -> bf16 [C][R] ----------------
__global__ __launch_bounds__(256) void k_transpose(const float* __restrict__ in,
                                                   bf16_t* __restrict__ out, int R, int C) {
  __shared__ float tile[32][33];
  const int tx = threadIdx.x & 31, ty = threadIdx.x >> 5;
  const int rb = blockIdx.y * 32, cb = blockIdx.x * 32;
#pragma unroll
  for (int i = 0; i < 32; i += 8)
    tile[ty + i][tx] = in[(size_t)(rb + ty + i) * C + (cb + tx)];
  __syncthreads();
#pragma unroll
  for (int i = 0; i < 32; i += 8)
    out[(size_t)(cb + ty + i) * R + (rb + tx)] = (bf16_t)tile[tx][ty + i];
}

// ---------------- bf16 GEMM: C[M][N] = A[M][K] * Bt[N][K]^T, f32 out ----------------
// m97-style 128x128 tile, BK=32, 4 waves, global_load_lds staging with
// source-side XOR swizzle so fragment ds_read_b128 is ~conflict-free.
__global__ __launch_bounds__(256) void k_gemm_bt(const bf16_t* __restrict__ A,
                                                 const bf16_t* __restrict__ Bt,
                                                 float* __restrict__ C,
                                                 int M, int N, int K,
                                                 int lda, int ldb, int ldc) {
  __shared__ __align__(16) bf16_t As[128 * 32];
  __shared__ __align__(16) bf16_t Bs[128 * 32];
  const int tid = threadIdx.x;
  const int lane = tid & 63, w = tid >> 6;
  const int c15 = lane & 15, g = lane >> 4;
  const int wr = w >> 1, wc = w & 1;
  const int brow = blockIdx.y * 128, bcol = blockIdx.x * 128;
  const int swzr = (c15 >> 1) & 3;

  const f32x4 fzero = {0.f, 0.f, 0.f, 0.f};
  f32x4 acc[4][4];
#pragma unroll
  for (int m = 0; m < 4; ++m)
#pragma unroll
    for (int n = 0; n < 4; ++n) acc[m][n] = fzero;

  for (int kt = 0; kt < K; kt += 32) {
    __syncthreads();
#pragma unroll
    for (int i = 0; i < 2; ++i) {
      const int c = tid + i * 256;
      const int row = c >> 2, pc = c & 3;
      const int lc = pc ^ ((row >> 1) & 3);   // swizzled source chunk
      gload16(A + (size_t)(brow + row) * lda + kt + lc * 8,
              As + (size_t)(w * 64 + i * 256) * 8);
      gload16(Bt + (size_t)(bcol + row) * ldb + kt + lc * 8,
              Bs + (size_t)(w * 64 + i * 256) * 8);
    }
    __syncthreads();
    bf16x8 af[4], bfm[4];
#pragma unroll
    for (int m = 0; m < 4; ++m) {
      const int row = wr * 64 + m * 16 + c15;
      af[m] = *(const bf16x8*)(As + row * 32 + (g ^ swzr) * 8);
    }
#pragma unroll
    for (int n = 0; n < 4; ++n) {
      const int row = wc * 64 + n * 16 + c15;
      bfm[n] = *(const bf16x8*)(Bs + row * 32 + (g ^ swzr) * 8);
    }
#pragma unroll
    for (int m = 0; m < 4; ++m)
#pragma unroll
      for (int n = 0; n < 4; ++n)
        acc[m][n] = mfma16(af[m], bfm[n], acc[m][n]);
  }
#pragma unroll
  for (int m = 0; m < 4; ++m)
#pragma unroll
    for (int n = 0; n < 4; ++n)
#pragma unroll
      for (int r = 0; r < 4; ++r) {
        const int row = brow + wr * 64 + m * 16 + g * 4 + r;
        const int col = bcol + wc * 64 + n * 16 + c15;
        C[(size_t)row * ldc + col] = acc[m][n][r];
      }
}

// ---------------- RoPE + pack to [B][H][S][D] bf16 (Q scaled by 1/sqrt(D)) ----------------
__global__ __launch_bounds__(256) void k_rope_pack(const float* __restrict__ QKV,
                                                   const int* __restrict__ pos_ids,
                                                   bf16_t* __restrict__ Qp,
                                                   bf16_t* __restrict__ Kp,
                                                   bf16_t* __restrict__ Vp) {
  const int token = blockIdx.x;           // b*2048 + s
  const int b = token >> 11, s = token & 2047;
  const int tid = threadIdx.x;
  __shared__ float cs[32], sn[32];
  if (tid < 32) {
    const float p = (float)pos_ids[token];
    const float freq = exp2f(-(2.0f * (float)tid) / 64.0f * log2f(10000.0f));
    const float a = p * freq;
    cs[tid] = cosf(a);
    sn[tid] = sinf(a);
  }
  __syncthreads();
  const float* row = QKV + (size_t)token * 3072;
#pragma unroll
  for (int i = 0; i < 4; ++i) {           // Q: 32 heads x 32 pairs
    const int p = tid + i * 256;
    const int hh = p >> 5, d2 = p & 31;
    const float q1 = row[hh * 64 + d2];
    const float q2 = row[hh * 64 + 32 + d2];
    const float c = cs[d2], sv = sn[d2];
    const size_t obase = (((size_t)b * 32 + hh) * 2048 + s) * 64 + d2;
    Qp[obase]      = (bf16_t)((q1 * c - q2 * sv) * 0.125f);
    Qp[obase + 32] = (bf16_t)((q2 * c + q1 * sv) * 0.125f);
  }
  {                                       // K: 8 heads x 32 pairs
    const int hh = tid >> 5, d2 = tid & 31;
    const float k1 = row[2048 + hh * 128 + d2];
    const float k2 = row[2048 + hh * 128 + 32 + d2];
    const float c = cs[d2], sv = sn[d2];
    const size_t obase = (((size_t)b * 8 + hh) * 2048 + s) * 64 + d2;
    Kp[obase]      = (bf16_t)(k1 * c - k2 * sv);
    Kp[obase + 32] = (bf16_t)(k2 * c + k1 * sv);
  }
#pragma unroll
  for (int i = 0; i < 2; ++i) {           // V copy: 8 heads x 64
    const int e = tid + i * 256;
    const int hh = e >> 6, d = e & 63;
    Vp[(((size_t)b * 8 + hh) * 2048 + s) * 64 + d] = (bf16_t)row[2048 + hh * 128 + 64 + d];
  }
}

// ---------------- causal GQA flash attention ----------------
// grid (S/64, NH, B); 4 waves, each owns 16 q rows; KVBLK=64.
__global__ __launch_bounds__(256) void k_attn(const bf16_t* __restrict__ Qp,
                                              const bf16_t* __restrict__ Kp,
                                              const bf16_t* __restrict__ Vp,
                                              bf16_t* __restrict__ ctx) {
  const int qtile = blockIdx.x;
  const int h = blockIdx.y;
  const int b = blockIdx.z;
  const int kvh = h >> 2;                 // GQA repeat_interleave(4)
  const int tid = threadIdx.x, lane = tid & 63, w = tid >> 6;
  const int c15 = lane & 15, g = lane >> 4;

  __shared__ __align__(16) bf16_t Ks[64 * 64];    // [kv][d], XOR-swizzled chunks
  __shared__ __align__(16) bf16_t Vts[64 * 64];   // [d][kv], XOR-swizzled chunks
  __shared__ __align__(16) bf16_t Pw[4][16 * 64]; // wave-private P, swizzled

  const int qbase = qtile * 64;
  const int q0w = qbase + w * 16;

  const bf16_t* Qrow = Qp + (((size_t)b * 32 + h) * 2048 + q0w + c15) * 64;
  const bf16x8 aq0 = *(const bf16x8*)(Qrow + g * 8);
  const bf16x8 aq1 = *(const bf16x8*)(Qrow + 32 + g * 8);

  const bf16_t* Kb = Kp + ((size_t)b * 8 + kvh) * (size_t)(2048 * 64);
  const bf16_t* Vb = Vp + ((size_t)b * 8 + kvh) * (size_t)(2048 * 64);

  const f32x4 fzero = {0.f, 0.f, 0.f, 0.f};
  f32x4 acc[4];
#pragma unroll
  for (int n = 0; n < 4; ++n) acc[n] = fzero;
  float mrow[4], lrow[4];
#pragma unroll
  for (int r = 0; r < 4; ++r) { mrow[r] = -1e30f; lrow[r] = 0.f; }

  const int vkv = tid & 63, vd0 = (tid >> 6) * 16;
  const int ntiles = qtile + 1;

  for (int t = 0; t < ntiles; ++t) {
    const int kvbase = t * 64;
    __syncthreads();
    // stage K tile via global_load_lds (swizzled source -> linear LDS)
#pragma unroll
    for (int i = 0; i < 2; ++i) {
      const int c = tid + i * 256;
      const int row = c >> 3, pc = c & 7;
      const int lc = pc ^ (row & 7);
      gload16(Kb + (size_t)(kvbase + row) * 64 + lc * 8,
              Ks + (size_t)(w * 64 + i * 256) * 8);
    }
    // stage V transposed via registers: Vts[d][kv]
    {
      const bf16_t* vs = Vb + (size_t)(kvbase + vkv) * 64 + vd0;
      union { uint4 u; ushort us[8]; } u0, u1;
      u0.u = *(const uint4*)(vs);
      u1.u = *(const uint4*)(vs + 8);
      ushort* vt = (ushort*)Vts;
#pragma unroll
      for (int j = 0; j < 8; ++j) {
        const int d = vd0 + j;
        vt[d * 64 + ((((vkv >> 3) ^ (d & 7)) << 3) | (vkv & 7))] = u0.us[j];
      }
#pragma unroll
      for (int j = 0; j < 8; ++j) {
        const int d = vd0 + 8 + j;
        vt[d * 64 + ((((vkv >> 3) ^ (d & 7)) << 3) | (vkv & 7))] = u1.us[j];
      }
    }
    __syncthreads();

    // S = Q K^T  (scale already folded into Q)
    f32x4 sv[4];
#pragma unroll
    for (int n = 0; n < 4; ++n) {
      const int row = n * 16 + c15;
      const bf16x8 bk0 = *(const bf16x8*)(Ks + row * 64 + ((g ^ (row & 7)) * 8));
      const bf16x8 bk1 = *(const bf16x8*)(Ks + row * 64 + (((4 + g) ^ (row & 7)) * 8));
      f32x4 s = fzero;
      s = mfma16(aq0, bk0, s);
      s = mfma16(aq1, bk1, s);
      sv[n] = s;
    }
    // causal mask: only the diagonal tile needs it
    if (t == ntiles - 1) {
#pragma unroll
      for (int n = 0; n < 4; ++n)
#pragma unroll
        for (int r = 0; r < 4; ++r) {
          const int col = kvbase + n * 16 + c15;
          const int rowq = q0w + g * 4 + r;
          if (col > rowq) sv[n][r] = -1e30f;
        }
    }
    // online softmax (rows live in 16-lane groups; reduce via shfl_xor 1..8)
    float tmax[4], alpha[4], rs[4];
#pragma unroll
    for (int r = 0; r < 4; ++r)
      tmax[r] = fmaxf(fmaxf(sv[0][r], sv[1][r]), fmaxf(sv[2][r], sv[3][r]));
#pragma unroll
    for (int off = 1; off < 16; off <<= 1)
#pragma unroll
      for (int r = 0; r < 4; ++r)
        tmax[r] = fmaxf(tmax[r], __shfl_xor(tmax[r], off));
#pragma unroll
    for (int r = 0; r < 4; ++r) {
      const float mn = fmaxf(mrow[r], tmax[r]);
      alpha[r] = __expf(mrow[r] - mn);
      mrow[r] = mn;
      rs[r] = 0.f;
    }
#pragma unroll
    for (int n = 0; n < 4; ++n)
#pragma unroll
      for (int r = 0; r < 4; ++r) {
        const float pv = __expf(sv[n][r] - mrow[r]);
        sv[n][r] = pv;
        rs[r] += pv;
      }
#pragma unroll
    for (int off = 1; off < 16; off <<= 1)
#pragma unroll
      for (int r = 0; r < 4; ++r)
        rs[r] += __shfl_xor(rs[r], off);
#pragma unroll
    for (int r = 0; r < 4; ++r) lrow[r] = lrow[r] * alpha[r] + rs[r];
#pragma unroll
    for (int n = 0; n < 4; ++n)
#pragma unroll
      for (int r = 0; r < 4; ++r) acc[n][r] *= alpha[r];

    // P -> wave-private LDS (swizzled), then read back as A-fragments
    bf16_t* pw = &Pw[w][0];
#pragma unroll
    for (int n = 0; n < 4; ++n)
#pragma unroll
      for (int r = 0; r < 4; ++r) {
        const int col = n * 16 + c15, rp = g * 4 + r;
        pw[rp * 64 + ((((col >> 3) ^ (rp & 7)) << 3) | (col & 7))] = (bf16_t)sv[n][r];
      }
    asm volatile("s_waitcnt lgkmcnt(0)" ::: "memory");
    const bf16x8 ap0 = *(const bf16x8*)(pw + c15 * 64 + ((g ^ (c15 & 7)) * 8));
    const bf16x8 ap1 = *(const bf16x8*)(pw + c15 * 64 + (((4 + g) ^ (c15 & 7)) * 8));
#pragma unroll
    for (int n = 0; n < 4; ++n) {
      const int row = n * 16 + c15;
      const bf16x8 bv0 = *(const bf16x8*)(Vts + row * 64 + ((g ^ (row & 7)) * 8));
      const bf16x8 bv1 = *(const bf16x8*)(Vts + row * 64 + (((4 + g) ^ (row & 7)) * 8));
      acc[n] = mfma16(ap0, bv0, acc[n]);
      acc[n] = mfma16(ap1, bv1, acc[n]);
    }
  }
  // epilogue: ctx[b*S + q][h*64 + d] bf16
#pragma unroll
  for (int n = 0; n < 4; ++n)
#pragma unroll
    for (int r = 0; r < 4; ++r) {
      const int rowq = q0w + g * 4 + r;
      const int col = h * 64 + n * 16 + c15;
      ctx[((size_t)b * 2048 + rowq) * 2048 + col] = (bf16_t)(acc[n][r] / lrow[r]);
    }
}

// ------------------------------------------------------------------
extern "C" void kernel_launch(void* const* d_in, const int* in_sizes, int n_in,
                              void* d_out, int out_size, void* d_ws, size_t ws_size,
                              hipStream_t stream) {
  const float* hs  = (const float*)d_in[0];
  const int*   pos = (const int*)d_in[1];
  const float* Wq  = (const float*)d_in[2];
  const float* Wkv = (const float*)d_in[3];
  const float* Wo  = (const float*)d_in[4];
  float* out = (float*)d_out;
  (void)in_sizes; (void)n_in; (void)out_size; (void)ws_size;

  // workspace carve-up (~130 MB total)
  char* p = (char*)d_ws;
  bf16_t* Xbf   = (bf16_t*)p; p += (size_t)4096 * 2048 * 2;
  bf16_t* Wqkvt = (bf16_t*)p; p += (size_t)3072 * 2048 * 2;  // [N=3072][K=2048]
  bf16_t* Wot   = (bf16_t*)p; p += (size_t)2048 * 2048 * 2;  // [N=2048][K=2048]
  float*  QKV   = (float*)p;  p += (size_t)4096 * 3072 * 4;  // [token][3072]
  bf16_t* Qp    = (bf16_t*)p; p += (size_t)2 * 32 * 2048 * 64 * 2;
  bf16_t* Kp    = (bf16_t*)p; p += (size_t)2 * 8 * 2048 * 64 * 2;
  bf16_t* Vp    = (bf16_t*)p; p += (size_t)2 * 8 * 2048 * 64 * 2;
  bf16_t* ctx   = (bf16_t*)p; p += (size_t)4096 * 2048 * 2;

  k_cvt_bf16<<<8192, 256, 0, stream>>>(hs, Xbf, 4096 * 2048);
  k_transpose<<<dim3(64, 64), 256, 0, stream>>>(Wq, Wqkvt, 2048, 2048);
  k_transpose<<<dim3(32, 64), 256, 0, stream>>>(Wkv, Wqkvt + (size_t)2048 * 2048, 2048, 1024);
  k_transpose<<<dim3(64, 64), 256, 0, stream>>>(Wo, Wot, 2048, 2048);
  // QKV = X @ [Wq | Wkv]
  k_gemm_bt<<<dim3(24, 32), 256, 0, stream>>>(Xbf, Wqkvt, QKV,
                                              4096, 3072, 2048, 2048, 2048, 3072);
  k_rope_pack<<<4096, 256, 0, stream>>>(QKV, pos, Qp, Kp, Vp);
  k_attn<<<dim3(32, 32, 2), 256, 0, stream>>>(Qp, Kp, Vp, ctx);
  // out = ctx @ Wo
  k_gemm_bt<<<dim3(16, 32), 256, 0, stream>>>(ctx, Wot, out,
                                              4096, 2048, 2048, 2048, 2048, 2048);
}